// Round 13
// baseline (234.436 us; speedup 1.0000x reference)
//
#include <hip/hip_runtime.h>
#include <hip/hip_bf16.h>
#include <stdint.h>

typedef unsigned short us;
typedef __bf16 bf8 __attribute__((ext_vector_type(8)));
typedef float  f4  __attribute__((ext_vector_type(4)));

typedef unsigned int __attribute__((address_space(1))) as1_uint;
typedef unsigned int __attribute__((address_space(3))) as3_uint;

__device__ __forceinline__ void async_ld16(const void* g, void* l) {
    __builtin_amdgcn_global_load_lds((as1_uint*)g, (as3_uint*)l, 16, 0, 0);
}

__device__ __forceinline__ us f2bf(float f) {
    __hip_bfloat16 h = __float2bfloat16(f);
    us u;
    __builtin_memcpy(&u, &h, 2);
    return u;
}

// hardware packed f32x2 -> bf16x2 (RNE).  No builtin on gfx950; inline asm.
__device__ __forceinline__ unsigned cvt_pk_bf16(float lo, float hi) {
    unsigned r;
    asm("v_cvt_pk_bf16_f32 %0, %1, %2" : "=v"(r) : "v"(lo), "v"(hi));
    return r;
}

__device__ __forceinline__ float fexp2(float x) {
#if __has_builtin(__builtin_amdgcn_exp2f)
    return __builtin_amdgcn_exp2f(x);
#else
    return exp2f(x);
#endif
}

// Q scale: 1/sqrt(64) * log2(e)  (flash uses raw v_exp_f32 = 2^x)
#define SCALE_Q 0.18033688011112042f

// ---------------- fp32 -> bf16 conversion of all inputs ----------------
__global__ __launch_bounds__(256)
void convert_all(const float* __restrict__ s0, const float* __restrict__ s1,
                 const float* __restrict__ s2, const float* __restrict__ s3,
                 const float* __restrict__ s4, const float* __restrict__ s5,
                 const float* __restrict__ s6,
                 us* __restrict__ d0, us* __restrict__ d1, us* __restrict__ d2,
                 us* __restrict__ d3, us* __restrict__ d4, us* __restrict__ d5,
                 us* __restrict__ d6)
{
    size_t i4 = (((size_t)blockIdx.x * 256) + threadIdx.x) << 2;
    const float* src; us* dst; size_t off;
    if (i4 < ((size_t)3 << 22)) {
        unsigned seg = (unsigned)(i4 >> 22);
        off = i4 & (((size_t)1 << 22) - 1);
        src = seg == 0 ? s0 : (seg == 1 ? s1 : s2);
        dst = seg == 0 ? d0 : (seg == 1 ? d1 : d2);
    } else {
        size_t j = i4 - ((size_t)3 << 22);
        unsigned seg = (unsigned)(j >> 20);
        off = j & (((size_t)1 << 20) - 1);
        src = seg == 0 ? s3 : (seg == 1 ? s4 : (seg == 2 ? s5 : s6));
        dst = seg == 0 ? d3 : (seg == 1 ? d4 : (seg == 2 ? d5 : d6));
    }
    float4 f = *(const float4*)(src + off);
    ushort4 o;
    o.x = f2bf(f.x); o.y = f2bf(f.y); o.z = f2bf(f.z); o.w = f2bf(f.w);
    *(ushort4*)(dst + off) = o;
}

// ---------------- bf16 MFMA GEMM: D = A-arg(MxK) x W-arg(NxK)^T + bias --------
// mfma(A_op = W-arg frags, B_op = A-arg frags):
//   D layout: lane l15 = A-arg row, regs (cr+r) = 4 consecutive W-arg rows.
// MODE 0: A=X(tokens), W=weights. bf16 out [B,H,S,64], b64 stores.
// MODE 1: fp32 out row-major [M,N], dwordx4 stores.
// MODE 2: swapped call (A-arg=Wv rows, W-arg=XV tokens): bf16 V^T [B,H,64,S],
//   tokens PERMUTED within each 64-tile to flash's logical-c order:
//   k=[kt|quad|r] -> c = (kt>>1)*32 + quad*8 + (kt&1)*4 + r, so flash's PV
//   B-operand comes straight from softmax registers (no P LDS round-trip).
// R5: cross-step dbuf/1-barrier REGRESSED; R6/R7: BK=64 neutral.
// R11: gemm_o BN=128 REGRESSED ~8us (1 block/CU kills the cross-block
// overlap that hides this structure's serialized per-step load drain).
// This is the proven R4 form (single-buffer, BK=32, 2 barriers/step).
template<int MODE, int BN>
__device__ __forceinline__
void gemm_body(const us* __restrict__ A, const us* __restrict__ W,
               const float* __restrict__ bias, void* __restrict__ out,
               float scale, int bx, int by)
{
    __shared__ us lA[128 * 32];
    __shared__ us lB[BN * 32];

    const int tid  = threadIdx.x;
    const int wv   = tid >> 6;
    const int lane = tid & 63;
    const int l15  = lane & 15;
    const int quad = lane >> 4;
    const int kq   = quad << 3;
    const int cr   = quad << 2;
    const int srow = lane >> 2;
    const int scol = (lane & 3) << 3;
    const int m0   = by << 7;
    const int n0   = bx * BN;
    constexpr int MJ = (BN == 128) ? 4 : 2;
    const int wm = (BN == 128) ? ((wv >> 1) << 6) : (wv << 5);
    const int wn = (BN == 128) ? ((wv & 1) << 6) : 0;

    f4 acc[4][MJ];
    const f4 zero = {0.f, 0.f, 0.f, 0.f};
#pragma unroll
    for (int i = 0; i < 4; ++i)
#pragma unroll
        for (int j = 0; j < MJ; ++j) acc[i][j] = zero;

    for (int kt = 0; kt < 1024; kt += 32) {
#pragma unroll
        for (int s = 0; s < 2; ++s) {
            const int chunk = wv * 2 + s;
            const int row   = chunk * 16 + srow;
            async_ld16(A + (size_t)(m0 + row) * 1024 + kt + scol, &lA[chunk * 512]);
        }
        if (BN == 128) {
#pragma unroll
            for (int s = 0; s < 2; ++s) {
                const int chunk = wv * 2 + s;
                const int row   = chunk * 16 + srow;
                async_ld16(W + (size_t)(n0 + row) * 1024 + kt + scol, &lB[chunk * 512]);
            }
        } else {
            const int row = wv * 16 + srow;
            async_ld16(W + (size_t)(n0 + row) * 1024 + kt + scol, &lB[wv * 512]);
        }
        __syncthreads();

        bf8 wf[4], xf[MJ];
#pragma unroll
        for (int i = 0; i < 4; ++i)
            wf[i] = *(const bf8*)&lB[(wn + i * 16 + l15) * 32 + kq];
#pragma unroll
        for (int j = 0; j < MJ; ++j)
            xf[j] = *(const bf8*)&lA[(wm + j * 16 + l15) * 32 + kq];
#pragma unroll
        for (int i = 0; i < 4; ++i)
#pragma unroll
            for (int j = 0; j < MJ; ++j)
                acc[i][j] = __builtin_amdgcn_mfma_f32_16x16x32_bf16(wf[i], xf[j], acc[i][j], 0, 0, 0);
        __syncthreads();
    }

    if (MODE == 2) {
        // V^T epilogue: lane=feature (Wv row), regs=4 consecutive tokens,
        // token position permuted k->c within each 64-token tile (see header).
        us* o = (us*)out;
#pragma unroll
        for (int j = 0; j < MJ; ++j) {
            const int f = m0 + wm + j * 16 + l15;       // h*64 + d
            const float bf_ = bias[f];
            const int hh = f >> 6, dd = f & 63;
#pragma unroll
            for (int i = 0; i < 4; ++i) {
                const int tokb = n0 + wn + i * 16 + cr;
                const int bb = tokb >> 11, ss_phys = tokb & 2047;
                const int k6 = ss_phys & 63;
                const int kt6 = k6 >> 4, qd = (k6 >> 2) & 3;
                const int c6 = ((kt6 >> 1) << 5) | (qd << 3) | ((kt6 & 1) << 2);
                const int ss = (ss_phys & ~63) | c6;
                us hp[4];
#pragma unroll
                for (int r = 0; r < 4; ++r) hp[r] = f2bf(acc[i][j][r] + bf_);
                uint2 w;
                w.x = (unsigned)hp[0] | ((unsigned)hp[1] << 16);
                w.y = (unsigned)hp[2] | ((unsigned)hp[3] << 16);
                *(uint2*)&o[((size_t)((bb * 16 + hh) * 64 + dd) << 11) + ss] = w;
            }
        }
        return;
    }

#pragma unroll
    for (int i = 0; i < 4; ++i) {
        const int gnb = n0 + wn + i * 16 + cr;
        const f4 bj = *(const f4*)&bias[gnb];
        if (MODE == 0) {
            us* o = (us*)out;
            const int hh = gnb >> 6, dd = gnb & 63;
#pragma unroll
            for (int j = 0; j < MJ; ++j) {
                const int gm = m0 + wm + j * 16 + l15;
                const int bb = gm >> 11, ss = gm & 2047;
                us hp[4];
#pragma unroll
                for (int r = 0; r < 4; ++r)
                    hp[r] = f2bf((acc[i][j][r] + bj[r]) * scale);
                uint2 w;
                w.x = (unsigned)hp[0] | ((unsigned)hp[1] << 16);
                w.y = (unsigned)hp[2] | ((unsigned)hp[3] << 16);
                *(uint2*)&o[(((size_t)(bb * 16 + hh) * 2048 + ss) << 6) + dd] = w;
            }
        } else {
            float* o = (float*)out;
#pragma unroll
            for (int j = 0; j < MJ; ++j) {
                const int gm = m0 + wm + j * 16 + l15;
                f4 v;
#pragma unroll
                for (int r = 0; r < 4; ++r) v[r] = acc[i][j][r] + bj[r];
                *(f4*)&o[((size_t)gm << 10) + gnb] = v;
            }
        }
    }
}

__global__ __launch_bounds__(256)
void gemm_qkv(const us* __restrict__ XQ, const us* __restrict__ XK,
              const us* __restrict__ XV,
              const us* __restrict__ WQ, const us* __restrict__ WK,
              const us* __restrict__ WV,
              const float* __restrict__ bq, const float* __restrict__ bk,
              const float* __restrict__ bv,
              us* __restrict__ QP, us* __restrict__ KP, us* __restrict__ VT)
{
    const int z = blockIdx.z;
    if (z == 2) {
        gemm_body<2, 128>(WV, XV, bv, VT, 1.0f, blockIdx.y, blockIdx.x);
        return;
    }
    const us* A = z == 0 ? XQ : XK;
    const us* W = z == 0 ? WQ : WK;
    const float* b = z == 0 ? bq : bk;
    us* o = z == 0 ? QP : KP;
    const float scale = z == 0 ? SCALE_Q : 1.0f;
    gemm_body<0, 128>(A, W, b, o, scale, blockIdx.x, blockIdx.y);
}

// R11 lesson: BN=128 here -> 256 blocks = 1 block/CU -> lost the cross-block
// latency hiding this structure depends on (+8us).  BN=64, 512 blocks, 2/CU.
__global__ __launch_bounds__(256)
void gemm_o(const us* __restrict__ A, const us* __restrict__ W,
            const float* __restrict__ bias, float* __restrict__ out)
{
    gemm_body<1, 64>(A, W, bias, out, 1.0f, blockIdx.x, blockIdx.y);
}

// ---------------- flash attention v14 (counted-vmcnt 2-deep pipeline) ------
// Q [B,H,S,64] (pre-scaled by log2e/8), K [B,H,S,64],
// V^T [B,H,64,S] with tokens c-permuted per 64-tile (see gemm MODE 2).
// Block = 512 threads = 8 waves, 32 q/wave.  Register-P + hw cvt_pk (v12,
// proven 60.3us).  R12: setprio was -1us -> removed.
// v14 (T4): replace __syncthreads' vmcnt(0) drain with counted waits:
//   - mask hoisted to an 8KB LDS table in the prologue (removes the wave-0
//     mask load from the loop; every wave now issues EXACTLY 2 gll/tile,
//     making the per-wave vmcnt count uniform and exact)
//   - 4 LDS buffers, 2-deep prefetch: tile t+2 issued at tile t
//   - per tile: s_waitcnt vmcnt(2) (tile-t pair done, t+1 pair stays in
//     flight ACROSS the barrier) + raw s_barrier (no compiler drain)
// Loads now get 2 full compute phases to land instead of <1.
// Race audit: buf[(t+2)&3] last read at t-2, all reads complete before
// barrier@t; each wave drains its OWN tile-t loads pre-barrier (m218/HK).
__global__ __launch_bounds__(512)
void flash_attn(const us* __restrict__ Qp, const us* __restrict__ Kp,
                const us* __restrict__ Vtp, const int* __restrict__ maskp,
                us* __restrict__ ctx)
{
    __shared__ us lK[4][64 * 64];     // 32 KB [key][d] swizzled content
    __shared__ us lVt[4][64 * 64];    // 32 KB [d][c] swizzled content
    __shared__ float lmaskA[2048];    //  8 KB whole-row mask (hoisted)

    const int tid  = threadIdx.x;
    const int wv   = tid >> 6;        // 0..7
    const int lane = tid & 63;
    const int l15  = lane & 15;
    const int quad = lane >> 4;
    const int cr   = quad << 2;
    const int l7   = l15 & 7;

    const int q0 = blockIdx.x << 8;   // 256 queries per block
    const int h  = blockIdx.y;
    const int b  = blockIdx.z;

    const size_t headoff = ((size_t)(b * 16 + h)) << 17;
    const us* Qh  = Qp  + headoff;
    const us* Kh  = Kp  + headoff;
    const us* Vth = Vtp + headoff;

    // gll staging geometry: each gll = 64 lanes x 16B = 8 rows of 128B.
    const int gr    = lane >> 3;                 // row within 8-row group
    const int gslot = ((lane & 7) ^ gr) << 3;    // swizzled source column (elems)

    // ---- prologue: hoist mask (512 thr x 4 ints -> f32 LDS table) ----
    {
        const int4 mi = *(const int4*)(maskp + ((size_t)b << 11) + (tid << 2));
        float4 mf;
        mf.x = mi.x == 0 ? 0.0f : 1.0f;
        mf.y = mi.y == 0 ? 0.0f : 1.0f;
        mf.z = mi.z == 0 ? 0.0f : 1.0f;
        mf.w = mi.w == 0 ? 0.0f : 1.0f;
        *(float4*)&lmaskA[tid << 2] = mf;
    }

    // Q B-frags for this wave's 32 queries, resident across the whole loop
    bf8 qf[2][2];
#pragma unroll
    for (int nt = 0; nt < 2; ++nt)
#pragma unroll
        for (int kb = 0; kb < 2; ++kb)
            qf[nt][kb] = *(const bf8*)(Qh + ((size_t)(q0 + wv * 32 + nt * 16 + l15) << 6)
                                          + kb * 32 + (quad << 3));

    const f4 zero = {0.f, 0.f, 0.f, 0.f};
    f4 of[4][2];                      // [dt][nt], C-layout col=q, rows=d
#pragma unroll
    for (int dt = 0; dt < 4; ++dt)
#pragma unroll
        for (int nt = 0; nt < 2; ++nt) of[dt][nt] = zero;
    float li[2] = {0.f, 0.f};

    // ISSUE: global -> LDS (async DMA), K and V^T, for buffer bi.
    // Exactly 2 vmem ops per wave per call -- the counted vmcnt relies on it.
#define FA_ISSUE(kt0, bi)                                                      \
    {                                                                          \
        const int rbase = wv * 8;                                              \
        const int r = rbase + gr;                                              \
        async_ld16(Kh + ((size_t)((kt0) + r) << 6) + gslot,                    \
                   &lK[bi][rbase * 64]);                                       \
        async_ld16(Vth + (size_t)r * 2048 + (kt0) + gslot,                     \
                   &lVt[bi][rbase * 64]);                                      \
    }

    // Drain Q loads + mask writes; zero outstanding vmem from here on.
    __syncthreads();

    // prologue: tiles 0 and 1 in flight (4 gll/wave outstanding)
    FA_ISSUE(0, 0);
    FA_ISSUE(64, 1);

    for (int t = 0; t < 32; ++t) {
        // counted drain: tile-t pair done; tile-(t+1) pair stays in flight
        if (t < 31) asm volatile("s_waitcnt vmcnt(2)" ::: "memory");
        else        asm volatile("s_waitcnt vmcnt(0)" ::: "memory");
        __builtin_amdgcn_s_barrier();
        __builtin_amdgcn_sched_barrier(0);
        if (t < 30) FA_ISSUE((t + 2) * 64, (t + 2) & 3);

        const us* lKc  = lK[t & 3];
        const us* lVtc = lVt[t & 3];
        const float* lmt = &lmaskA[t << 6];

        // ---- S^T = K.Q^T, kt-streamed softmax, packs kept in registers ----
        float rs[2] = {0.f, 0.f};
        unsigned pkx[4][2], pky[4][2];   // [kt][nt], fully unrolled static idx
#pragma unroll
        for (int kt = 0; kt < 4; ++kt) {
            const int krow = (kt * 16 + l15) << 6;
            bf8 kf0 = *(const bf8*)&lKc[krow + ((quad ^ l7) << 3)];
            bf8 kf1 = *(const bf8*)&lKc[krow + (((4 + quad) ^ l7) << 3)];
            f4 st[2];
#pragma unroll
            for (int nt = 0; nt < 2; ++nt) {
                st[nt] = __builtin_amdgcn_mfma_f32_16x16x32_bf16(kf0, qf[nt][0], zero, 0, 0, 0);
                st[nt] = __builtin_amdgcn_mfma_f32_16x16x32_bf16(kf1, qf[nt][1], st[nt], 0, 0, 0);
            }
            const f4 mr = *(const f4*)&lmt[kt * 16 + cr];
#pragma unroll
            for (int nt = 0; nt < 2; ++nt) {
                float p[4];
#pragma unroll
                for (int r = 0; r < 4; ++r) {
                    p[r] = fexp2(st[nt][r]) * mr[r];
                    rs[nt] += p[r];
                }
                pkx[kt][nt] = cvt_pk_bf16(p[0], p[1]);
                pky[kt][nt] = cvt_pk_bf16(p[2], p[3]);
            }
        }
#pragma unroll
        for (int nt = 0; nt < 2; ++nt) {
            float r2 = rs[nt];
            r2 += __shfl_xor(r2, 16, 64);
            r2 += __shfl_xor(r2, 32, 64);
            li[nt] += r2;
        }

        // ---- O^T += V^T . P^T  (P operand straight from registers) ----
#pragma unroll
        for (int kb = 0; kb < 2; ++kb) {
            bf8 pfr[2];
#pragma unroll
            for (int nt = 0; nt < 2; ++nt) {
                uint4 u;
                u.x = pkx[2 * kb][nt];
                u.y = pky[2 * kb][nt];
                u.z = pkx[2 * kb + 1][nt];
                u.w = pky[2 * kb + 1][nt];
                __builtin_memcpy(&pfr[nt], &u, 16);
            }
#pragma unroll
            for (int dt = 0; dt < 4; ++dt) {
                bf8 vf = *(const bf8*)&lVtc[((dt * 16 + l15) << 6) + (((kb * 4 + quad) ^ l7) << 3)];
#pragma unroll
                for (int nt = 0; nt < 2; ++nt)
                    of[dt][nt] = __builtin_amdgcn_mfma_f32_16x16x32_bf16(vf, pfr[nt], of[dt][nt], 0, 0, 0);
            }
        }
    }
#undef FA_ISSUE

    // ---- epilogue: ctx[b, tok, h*64+d] = O / l ----
#pragma unroll
    for (int nt = 0; nt < 2; ++nt) {
        const float linv = 1.0f / li[nt];
        const int tok = q0 + wv * 32 + nt * 16 + l15;
        const size_t rowb = (((size_t)(b * 2048 + tok)) << 10) + (h << 6);
#pragma unroll
        for (int dt = 0; dt < 4; ++dt) {
            uint2 w;
            w.x = cvt_pk_bf16(of[dt][nt][0] * linv, of[dt][nt][1] * linv);
            w.y = cvt_pk_bf16(of[dt][nt][2] * linv, of[dt][nt][3] * linv);
            *(uint2*)&ctx[rowb + dt * 16 + cr] = w;
        }
    }
}

// ---------------- launch ----------------
extern "C" void kernel_launch(void* const* d_in, const int* in_sizes, int n_in,
                              void* d_out, int out_size, void* d_ws, size_t ws_size,
                              hipStream_t stream)
{
    const float* q    = (const float*)d_in[0];
    const float* k    = (const float*)d_in[1];
    const float* v    = (const float*)d_in[2];
    const int*   mask = (const int*)d_in[3];
    const float* Wq   = (const float*)d_in[4];
    const float* bq   = (const float*)d_in[5];
    const float* Wk   = (const float*)d_in[6];
    const float* bk   = (const float*)d_in[7];
    const float* Wv   = (const float*)d_in[8];
    const float* bv   = (const float*)d_in[9];
    const float* Wo   = (const float*)d_in[10];
    const float* bo   = (const float*)d_in[11];
    float* out = (float*)d_out;

    us* ws  = (us*)d_ws;
    us* XQ  = ws;                   // 4096x1024
    us* XK  = ws + 4194304;
    us* XV  = ws + 8388608;
    us* WQb = ws + 12582912;        // 1024x1024 each
    us* WKb = ws + 13631488;
    us* WVb = ws + 14680064;
    us* WOb = ws + 15728640;
    us* QP  = ws + 16777216;        // [B,H,S,64]
    us* KP  = ws + 20971520;        // [B,H,S,64]
    us* VT  = ws + 25165824;        // [B,H,64,S] (c-permuted per 64-tile)
    us* CTX = XQ;                   // reuses XQ (dead by then)

    convert_all<<<16384, 256, 0, stream>>>(q, k, v, Wq, Wk, Wv, Wo,
                                           XQ, XK, XV, WQb, WKb, WVb, WOb);
    gemm_qkv<<<dim3(8, 32, 3), 256, 0, stream>>>(XQ, XK, XV, WQb, WKb, WVb,
                                                 bq, bk, bv, QP, KP, VT);
    flash_attn<<<dim3(8, 16, 2), 512, 0, stream>>>(QP, KP, VT, mask, CTX);
    gemm_o<<<dim3(16, 32), 256, 0, stream>>>(CTX, WOb, bo, out);
}

// Round 14
// 228.332 us; speedup vs baseline: 1.0267x; 1.0267x over previous
//
#include <hip/hip_runtime.h>
#include <hip/hip_bf16.h>
#include <stdint.h>

typedef unsigned short us;
typedef __bf16 bf8 __attribute__((ext_vector_type(8)));
typedef float  f4  __attribute__((ext_vector_type(4)));

typedef unsigned int __attribute__((address_space(1))) as1_uint;
typedef unsigned int __attribute__((address_space(3))) as3_uint;

__device__ __forceinline__ void async_ld16(const void* g, void* l) {
    __builtin_amdgcn_global_load_lds((as1_uint*)g, (as3_uint*)l, 16, 0, 0);
}

__device__ __forceinline__ us f2bf(float f) {
    __hip_bfloat16 h = __float2bfloat16(f);
    us u;
    __builtin_memcpy(&u, &h, 2);
    return u;
}

// hardware packed f32x2 -> bf16x2 (RNE).  No builtin on gfx950; inline asm.
__device__ __forceinline__ unsigned cvt_pk_bf16(float lo, float hi) {
    unsigned r;
    asm("v_cvt_pk_bf16_f32 %0, %1, %2" : "=v"(r) : "v"(lo), "v"(hi));
    return r;
}

__device__ __forceinline__ float fexp2(float x) {
#if __has_builtin(__builtin_amdgcn_exp2f)
    return __builtin_amdgcn_exp2f(x);
#else
    return exp2f(x);
#endif
}

// Q scale: 1/sqrt(64) * log2(e)  (flash uses raw v_exp_f32 = 2^x)
#define SCALE_Q 0.18033688011112042f

// ---------------- fp32 -> bf16 conversion of all inputs ----------------
__global__ __launch_bounds__(256)
void convert_all(const float* __restrict__ s0, const float* __restrict__ s1,
                 const float* __restrict__ s2, const float* __restrict__ s3,
                 const float* __restrict__ s4, const float* __restrict__ s5,
                 const float* __restrict__ s6,
                 us* __restrict__ d0, us* __restrict__ d1, us* __restrict__ d2,
                 us* __restrict__ d3, us* __restrict__ d4, us* __restrict__ d5,
                 us* __restrict__ d6)
{
    size_t i4 = (((size_t)blockIdx.x * 256) + threadIdx.x) << 2;
    const float* src; us* dst; size_t off;
    if (i4 < ((size_t)3 << 22)) {
        unsigned seg = (unsigned)(i4 >> 22);
        off = i4 & (((size_t)1 << 22) - 1);
        src = seg == 0 ? s0 : (seg == 1 ? s1 : s2);
        dst = seg == 0 ? d0 : (seg == 1 ? d1 : d2);
    } else {
        size_t j = i4 - ((size_t)3 << 22);
        unsigned seg = (unsigned)(j >> 20);
        off = j & (((size_t)1 << 20) - 1);
        src = seg == 0 ? s3 : (seg == 1 ? s4 : (seg == 2 ? s5 : s6));
        dst = seg == 0 ? d3 : (seg == 1 ? d4 : (seg == 2 ? d5 : d6));
    }
    float4 f = *(const float4*)(src + off);
    ushort4 o;
    o.x = f2bf(f.x); o.y = f2bf(f.y); o.z = f2bf(f.z); o.w = f2bf(f.w);
    *(ushort4*)(dst + off) = o;
}

// ---------------- bf16 MFMA GEMM: D = A-arg(MxK) x W-arg(NxK)^T + bias --------
// mfma(A_op = W-arg frags, B_op = A-arg frags):
//   D layout: lane l15 = A-arg row, regs (cr+r) = 4 consecutive W-arg rows.
// MODE 0: A=X(tokens), W=weights. bf16 out [B,H,S,64], b64 stores.
// MODE 1: fp32 out row-major [M,N], dwordx4 stores.
// MODE 2: swapped call (A-arg=Wv rows, W-arg=XV tokens): bf16 V^T [B,H,64,S],
//   tokens PERMUTED within each 64-tile to flash's logical-c order:
//   k=[kt|quad|r] -> c = (kt>>1)*32 + quad*8 + (kt&1)*4 + r, so flash's PV
//   B-operand comes straight from softmax registers (no P LDS round-trip).
// R5: cross-step dbuf/1-barrier REGRESSED; R6/R7: BK=64 neutral.
// R11: gemm_o BN=128 REGRESSED ~8us (1 block/CU kills cross-block overlap).
// R13 (T1): grids TRANSPOSED so linear-id%8 = TOKEN panel, not weight panel.
// Blocks dispatch round-robin over 8 XCDs by linear id; with bx fastest each
// XCD streamed the ENTIRE 25MB A set (W was local).  With by fastest each
// XCD holds 4 token panels (1MB) + full W set (2MB) -- both L2-resident.
// This is the proven R4 body (single-buffer, BK=32, 2 barriers/step).
template<int MODE, int BN>
__device__ __forceinline__
void gemm_body(const us* __restrict__ A, const us* __restrict__ W,
               const float* __restrict__ bias, void* __restrict__ out,
               float scale, int bx, int by)
{
    __shared__ us lA[128 * 32];
    __shared__ us lB[BN * 32];

    const int tid  = threadIdx.x;
    const int wv   = tid >> 6;
    const int lane = tid & 63;
    const int l15  = lane & 15;
    const int quad = lane >> 4;
    const int kq   = quad << 3;
    const int cr   = quad << 2;
    const int srow = lane >> 2;
    const int scol = (lane & 3) << 3;
    const int m0   = by << 7;
    const int n0   = bx * BN;
    constexpr int MJ = (BN == 128) ? 4 : 2;
    const int wm = (BN == 128) ? ((wv >> 1) << 6) : (wv << 5);
    const int wn = (BN == 128) ? ((wv & 1) << 6) : 0;

    f4 acc[4][MJ];
    const f4 zero = {0.f, 0.f, 0.f, 0.f};
#pragma unroll
    for (int i = 0; i < 4; ++i)
#pragma unroll
        for (int j = 0; j < MJ; ++j) acc[i][j] = zero;

    for (int kt = 0; kt < 1024; kt += 32) {
#pragma unroll
        for (int s = 0; s < 2; ++s) {
            const int chunk = wv * 2 + s;
            const int row   = chunk * 16 + srow;
            async_ld16(A + (size_t)(m0 + row) * 1024 + kt + scol, &lA[chunk * 512]);
        }
        if (BN == 128) {
#pragma unroll
            for (int s = 0; s < 2; ++s) {
                const int chunk = wv * 2 + s;
                const int row   = chunk * 16 + srow;
                async_ld16(W + (size_t)(n0 + row) * 1024 + kt + scol, &lB[chunk * 512]);
            }
        } else {
            const int row = wv * 16 + srow;
            async_ld16(W + (size_t)(n0 + row) * 1024 + kt + scol, &lB[wv * 512]);
        }
        __syncthreads();

        bf8 wf[4], xf[MJ];
#pragma unroll
        for (int i = 0; i < 4; ++i)
            wf[i] = *(const bf8*)&lB[(wn + i * 16 + l15) * 32 + kq];
#pragma unroll
        for (int j = 0; j < MJ; ++j)
            xf[j] = *(const bf8*)&lA[(wm + j * 16 + l15) * 32 + kq];
#pragma unroll
        for (int i = 0; i < 4; ++i)
#pragma unroll
            for (int j = 0; j < MJ; ++j)
                acc[i][j] = __builtin_amdgcn_mfma_f32_16x16x32_bf16(wf[i], xf[j], acc[i][j], 0, 0, 0);
        __syncthreads();
    }

    if (MODE == 2) {
        // V^T epilogue: lane=feature (Wv row), regs=4 consecutive tokens,
        // token position permuted k->c within each 64-token tile (see header).
        us* o = (us*)out;
#pragma unroll
        for (int j = 0; j < MJ; ++j) {
            const int f = m0 + wm + j * 16 + l15;       // h*64 + d
            const float bf_ = bias[f];
            const int hh = f >> 6, dd = f & 63;
#pragma unroll
            for (int i = 0; i < 4; ++i) {
                const int tokb = n0 + wn + i * 16 + cr;
                const int bb = tokb >> 11, ss_phys = tokb & 2047;
                const int k6 = ss_phys & 63;
                const int kt6 = k6 >> 4, qd = (k6 >> 2) & 3;
                const int c6 = ((kt6 >> 1) << 5) | (qd << 3) | ((kt6 & 1) << 2);
                const int ss = (ss_phys & ~63) | c6;
                us hp[4];
#pragma unroll
                for (int r = 0; r < 4; ++r) hp[r] = f2bf(acc[i][j][r] + bf_);
                uint2 w;
                w.x = (unsigned)hp[0] | ((unsigned)hp[1] << 16);
                w.y = (unsigned)hp[2] | ((unsigned)hp[3] << 16);
                *(uint2*)&o[((size_t)((bb * 16 + hh) * 64 + dd) << 11) + ss] = w;
            }
        }
        return;
    }

#pragma unroll
    for (int i = 0; i < 4; ++i) {
        const int gnb = n0 + wn + i * 16 + cr;
        const f4 bj = *(const f4*)&bias[gnb];
        if (MODE == 0) {
            us* o = (us*)out;
            const int hh = gnb >> 6, dd = gnb & 63;
#pragma unroll
            for (int j = 0; j < MJ; ++j) {
                const int gm = m0 + wm + j * 16 + l15;
                const int bb = gm >> 11, ss = gm & 2047;
                us hp[4];
#pragma unroll
                for (int r = 0; r < 4; ++r)
                    hp[r] = f2bf((acc[i][j][r] + bj[r]) * scale);
                uint2 w;
                w.x = (unsigned)hp[0] | ((unsigned)hp[1] << 16);
                w.y = (unsigned)hp[2] | ((unsigned)hp[3] << 16);
                *(uint2*)&o[(((size_t)(bb * 16 + hh) * 2048 + ss) << 6) + dd] = w;
            }
        } else {
            float* o = (float*)out;
#pragma unroll
            for (int j = 0; j < MJ; ++j) {
                const int gm = m0 + wm + j * 16 + l15;
                f4 v;
#pragma unroll
                for (int r = 0; r < 4; ++r) v[r] = acc[i][j][r] + bj[r];
                *(f4*)&o[((size_t)gm << 10) + gnb] = v;
            }
        }
    }
}

// R13: grid transposed to (32, 8, 3); blockIdx.x = token panel (by for
// modes 0; bx for mode 2), so linear-id%8 spreads TOKEN panels over XCDs.
__global__ __launch_bounds__(256)
void gemm_qkv(const us* __restrict__ XQ, const us* __restrict__ XK,
              const us* __restrict__ XV,
              const us* __restrict__ WQ, const us* __restrict__ WK,
              const us* __restrict__ WV,
              const float* __restrict__ bq, const float* __restrict__ bk,
              const float* __restrict__ bv,
              us* __restrict__ QP, us* __restrict__ KP, us* __restrict__ VT)
{
    const int z = blockIdx.z;
    if (z == 2) {
        gemm_body<2, 128>(WV, XV, bv, VT, 1.0f, blockIdx.x, blockIdx.y);
        return;
    }
    const us* A = z == 0 ? XQ : XK;
    const us* W = z == 0 ? WQ : WK;
    const float* b = z == 0 ? bq : bk;
    us* o = z == 0 ? QP : KP;
    const float scale = z == 0 ? SCALE_Q : 1.0f;
    gemm_body<0, 128>(A, W, b, o, scale, blockIdx.y, blockIdx.x);
}

// R11: BN=64 (512 blocks, 2/CU).  R13: grid transposed to (32,16).
__global__ __launch_bounds__(256)
void gemm_o(const us* __restrict__ A, const us* __restrict__ W,
            const float* __restrict__ bias, float* __restrict__ out)
{
    gemm_body<1, 64>(A, W, bias, out, 1.0f, blockIdx.y, blockIdx.x);
}

// ---------------- flash attention v12 (register P + hw cvt_pk) -------------
// Q [B,H,S,64] (pre-scaled by log2e/8), K [B,H,S,64],
// V^T [B,H,64,S] with tokens c-permuted per 64-tile (see gemm MODE 2).
// Block = 512 threads = 8 waves, 32 q/wave.  PROVEN 60.3us.
// R12: setprio NEUTRAL-NEGATIVE (removed).  R13: counted-vmcnt 2-deep (v14)
// NEUTRAL (removed) -- loads already land within one compute phase; flash's
// time is distributed across LDS/VALU/TRANS/MFMA pipes with no single
// dominant serializer at this structure.
// Register-P: softmax packs stay in VGPRs and feed PV directly (V^T was
// pre-permuted to P's natural register order).  Bank conflicts = 0.
// Staging: gll DMA, pre-swizzled global source, linear LDS dest, one
// barrier/tile, tile t+1 in flight across tile-t compute.
__global__ __launch_bounds__(512)
void flash_attn(const us* __restrict__ Qp, const us* __restrict__ Kp,
                const us* __restrict__ Vtp, const int* __restrict__ maskp,
                us* __restrict__ ctx)
{
    __shared__ us lK[2][64 * 64];     // 16 KB [key][d] swizzled content
    __shared__ us lVt[2][64 * 64];    // 16 KB [d][c] swizzled content
    __shared__ float lmask[2][64];

    const int tid  = threadIdx.x;
    const int wv   = tid >> 6;        // 0..7
    const int lane = tid & 63;
    const int l15  = lane & 15;
    const int quad = lane >> 4;
    const int cr   = quad << 2;
    const int l7   = l15 & 7;

    const int q0 = blockIdx.x << 8;   // 256 queries per block
    const int h  = blockIdx.y;
    const int b  = blockIdx.z;

    const size_t headoff = ((size_t)(b * 16 + h)) << 17;
    const us* Qh  = Qp  + headoff;
    const us* Kh  = Kp  + headoff;
    const us* Vth = Vtp + headoff;

    // gll staging geometry: each gll = 64 lanes x 16B = 8 rows of 128B.
    const int gr    = lane >> 3;                 // row within 8-row group
    const int gslot = ((lane & 7) ^ gr) << 3;    // swizzled source column (elems)

    // Q B-frags for this wave's 32 queries, resident across the whole loop
    bf8 qf[2][2];
#pragma unroll
    for (int nt = 0; nt < 2; ++nt)
#pragma unroll
        for (int kb = 0; kb < 2; ++kb)
            qf[nt][kb] = *(const bf8*)(Qh + ((size_t)(q0 + wv * 32 + nt * 16 + l15) << 6)
                                          + kb * 32 + (quad << 3));

    const f4 zero = {0.f, 0.f, 0.f, 0.f};
    f4 of[4][2];                      // [dt][nt], C-layout col=q, rows=d
#pragma unroll
    for (int dt = 0; dt < 4; ++dt)
#pragma unroll
        for (int nt = 0; nt < 2; ++nt) of[dt][nt] = zero;
    float li[2] = {0.f, 0.f};

    // ISSUE: global -> LDS (async DMA), K and V^T, + mask, for buffer bi
#define FA_ISSUE(kt0, bi)                                                      \
    {                                                                          \
        const int rbase = wv * 8;                                              \
        const int r = rbase + gr;                                              \
        async_ld16(Kh + ((size_t)((kt0) + r) << 6) + gslot,                    \
                   &lK[bi][rbase * 64]);                                       \
        async_ld16(Vth + (size_t)r * 2048 + (kt0) + gslot,                     \
                   &lVt[bi][rbase * 64]);                                      \
        if (tid < 64)                                                          \
            lmask[bi][tid] =                                                   \
                (maskp[((size_t)b << 11) + (kt0) + tid] == 0) ? 0.0f : 1.0f;   \
    }

    // prologue: tile 0 loads in flight
    FA_ISSUE(0, 0);

    for (int t = 0; t < 32; ++t) {
        const int cur = t & 1;
        __syncthreads();              // drains tile-t loads; frees buf[cur^1]
        if (t < 31) FA_ISSUE((t + 1) * 64, cur ^ 1);

        const us* lKc  = lK[cur];
        const us* lVtc = lVt[cur];

        // ---- S^T = K.Q^T, kt-streamed softmax, packs kept in registers ----
        float rs[2] = {0.f, 0.f};
        unsigned pkx[4][2], pky[4][2];   // [kt][nt], fully unrolled static idx
#pragma unroll
        for (int kt = 0; kt < 4; ++kt) {
            const int krow = (kt * 16 + l15) << 6;
            bf8 kf0 = *(const bf8*)&lKc[krow + ((quad ^ l7) << 3)];
            bf8 kf1 = *(const bf8*)&lKc[krow + (((4 + quad) ^ l7) << 3)];
            f4 st[2];
#pragma unroll
            for (int nt = 0; nt < 2; ++nt) {
                st[nt] = __builtin_amdgcn_mfma_f32_16x16x32_bf16(kf0, qf[nt][0], zero, 0, 0, 0);
                st[nt] = __builtin_amdgcn_mfma_f32_16x16x32_bf16(kf1, qf[nt][1], st[nt], 0, 0, 0);
            }
            const f4 mr = *(const f4*)&lmask[cur][kt * 16 + cr];
#pragma unroll
            for (int nt = 0; nt < 2; ++nt) {
                float p[4];
#pragma unroll
                for (int r = 0; r < 4; ++r) {
                    p[r] = fexp2(st[nt][r]) * mr[r];
                    rs[nt] += p[r];
                }
                pkx[kt][nt] = cvt_pk_bf16(p[0], p[1]);
                pky[kt][nt] = cvt_pk_bf16(p[2], p[3]);
            }
        }
#pragma unroll
        for (int nt = 0; nt < 2; ++nt) {
            float r2 = rs[nt];
            r2 += __shfl_xor(r2, 16, 64);
            r2 += __shfl_xor(r2, 32, 64);
            li[nt] += r2;
        }

        // ---- O^T += V^T . P^T  (P operand straight from registers) ----
#pragma unroll
        for (int kb = 0; kb < 2; ++kb) {
            bf8 pfr[2];
#pragma unroll
            for (int nt = 0; nt < 2; ++nt) {
                uint4 u;
                u.x = pkx[2 * kb][nt];
                u.y = pky[2 * kb][nt];
                u.z = pkx[2 * kb + 1][nt];
                u.w = pky[2 * kb + 1][nt];
                __builtin_memcpy(&pfr[nt], &u, 16);
            }
#pragma unroll
            for (int dt = 0; dt < 4; ++dt) {
                bf8 vf = *(const bf8*)&lVtc[((dt * 16 + l15) << 6) + (((kb * 4 + quad) ^ l7) << 3)];
#pragma unroll
                for (int nt = 0; nt < 2; ++nt)
                    of[dt][nt] = __builtin_amdgcn_mfma_f32_16x16x32_bf16(vf, pfr[nt], of[dt][nt], 0, 0, 0);
            }
        }
    }
#undef FA_ISSUE

    // ---- epilogue: ctx[b, tok, h*64+d] = O / l ----
#pragma unroll
    for (int nt = 0; nt < 2; ++nt) {
        const float linv = 1.0f / li[nt];
        const int tok = q0 + wv * 32 + nt * 16 + l15;
        const size_t rowb = (((size_t)(b * 2048 + tok)) << 10) + (h << 6);
#pragma unroll
        for (int dt = 0; dt < 4; ++dt) {
            uint2 w;
            w.x = cvt_pk_bf16(of[dt][nt][0] * linv, of[dt][nt][1] * linv);
            w.y = cvt_pk_bf16(of[dt][nt][2] * linv, of[dt][nt][3] * linv);
            *(uint2*)&ctx[rowb + dt * 16 + cr] = w;
        }
    }
}

// ---------------- launch ----------------
extern "C" void kernel_launch(void* const* d_in, const int* in_sizes, int n_in,
                              void* d_out, int out_size, void* d_ws, size_t ws_size,
                              hipStream_t stream)
{
    const float* q    = (const float*)d_in[0];
    const float* k    = (const float*)d_in[1];
    const float* v    = (const float*)d_in[2];
    const int*   mask = (const int*)d_in[3];
    const float* Wq   = (const float*)d_in[4];
    const float* bq   = (const float*)d_in[5];
    const float* Wk   = (const float*)d_in[6];
    const float* bk   = (const float*)d_in[7];
    const float* Wv   = (const float*)d_in[8];
    const float* bv   = (const float*)d_in[9];
    const float* Wo   = (const float*)d_in[10];
    const float* bo   = (const float*)d_in[11];
    float* out = (float*)d_out;

    us* ws  = (us*)d_ws;
    us* XQ  = ws;                   // 4096x1024
    us* XK  = ws + 4194304;
    us* XV  = ws + 8388608;
    us* WQb = ws + 12582912;        // 1024x1024 each
    us* WKb = ws + 13631488;
    us* WVb = ws + 14680064;
    us* WOb = ws + 15728640;
    us* QP  = ws + 16777216;        // [B,H,S,64]
    us* KP  = ws + 20971520;        // [B,H,S,64]
    us* VT  = ws + 25165824;        // [B,H,64,S] (c-permuted per 64-tile)
    us* CTX = XQ;                   // reuses XQ (dead by then)

    convert_all<<<16384, 256, 0, stream>>>(q, k, v, Wq, Wk, Wv, Wo,
                                           XQ, XK, XV, WQb, WKb, WVb, WOb);
    gemm_qkv<<<dim3(32, 8, 3), 256, 0, stream>>>(XQ, XK, XV, WQb, WKb, WVb,
                                                 bq, bk, bv, QP, KP, VT);
    flash_attn<<<dim3(8, 16, 2), 512, 0, stream>>>(QP, KP, VT, mask, CTX);
    gemm_o<<<dim3(32, 16), 256, 0, stream>>>(CTX, WOb, bo, out);
}